// Round 3
// baseline (466.927 us; speedup 1.0000x reference)
//
#include <hip/hip_runtime.h>
#include <hip/hip_bf16.h>
#include <stdint.h>

#define D_MODEL 1024
#define NHEADS  16
#define DH      64
#define NBATCH  4
#define SEQLEN  4096
#define MROWS   (NBATCH*SEQLEN)   // 16384
#define EPSV    1e-10f

typedef __hip_bfloat16 bf16;
typedef unsigned short ushort_t;
typedef __attribute__((ext_vector_type(8))) short short8;   // 8 bf16 (4 VGPRs)
typedef __attribute__((ext_vector_type(4))) float f32x4;

struct __align__(8) bf16x4s { bf16 a, b, c, d; };

__device__ __forceinline__ void async_copy16(void* lds, const void* g) {
  __builtin_amdgcn_global_load_lds(
      (const __attribute__((address_space(1))) unsigned int*)(uintptr_t)g,
      (__attribute__((address_space(3))) unsigned int*)(uintptr_t)lds,
      16, 0, 0);
}

__device__ __forceinline__ short f2bf_bits(float v) {
  bf16 b = __float2bfloat16(v);
  short s; __builtin_memcpy(&s, &b, 2); return s;
}
__device__ __forceinline__ float bfbits_to_f(ushort_t u) {
  return __uint_as_float(((unsigned int)u) << 16);
}

// ---------------- f32 -> bf16 conversion (vectorized, exact grid) ----------------
__global__ __launch_bounds__(256)
void cvt_bf16(const float* __restrict__ s, bf16* __restrict__ d) {
  const int i = blockIdx.x * 256 + threadIdx.x;
  const f32x4 v = ((const f32x4*)s)[i];
  bf16x4s o;
  o.a = __float2bfloat16(v[0]);
  o.b = __float2bfloat16(v[1]);
  o.c = __float2bfloat16(v[2]);
  o.d = __float2bfloat16(v[3]);
  ((bf16x4s*)d)[i] = o;
}

// ---------------- weight transpose + cvt (W[K,N] f32 -> WT[N,K] bf16) ----------------
__global__ void transpose4(const float* __restrict__ s0, const float* __restrict__ s1,
                           const float* __restrict__ s2, const float* __restrict__ s3,
                           bf16* __restrict__ d0, bf16* __restrict__ d1,
                           bf16* __restrict__ d2, bf16* __restrict__ d3) {
  const float* s; bf16* d;
  switch (blockIdx.z) {
    case 0: s = s0; d = d0; break;
    case 1: s = s1; d = d1; break;
    case 2: s = s2; d = d2; break;
    default: s = s3; d = d3; break;
  }
  __shared__ float tile[32][33];
  int x = blockIdx.x*32 + threadIdx.x;
  int y = blockIdx.y*32 + threadIdx.y;
  tile[threadIdx.y][threadIdx.x] = s[(size_t)y*D_MODEL + x];
  __syncthreads();
  int xo = blockIdx.y*32 + threadIdx.x;
  int yo = blockIdx.x*32 + threadIdx.y;
  d[(size_t)yo*D_MODEL + xo] = __float2bfloat16(tile[threadIdx.x][threadIdx.y]);
}

// ---------------- GEMM: C[M,N] = act(A[M,K] @ BT[N,K]^T + bias) ----------------
// 256x256 tile, 8-phase m201-style schedule. BK=64, 2 K-tiles/iteration.
// 8 waves (2M x 4N, 128x64 C each), LDS 128 KB (2 dbuf x 256 x 64 bf16 x A,B),
// 1 block/CU, grid 256 blocks (XCD-swizzled).
// Per phase: 12 ds_read_b128 (one C-quadrant's frags) || stage 1 half-tile
// (2 global_load_lds) -> s_barrier -> lgkmcnt(0) -> setprio+16 MFMA -> s_barrier.
// Counted vmcnt(4) only at ends of phases 3 and 7 (epilogue drains to 0).
// Half-tile lifetime schedule guarantees each stage targets a barrier-certified
// dead half and each half is vmcnt+barrier certified before its first read.
// LDS swizzle: 16B group g of row r stored at g^(r&7) (pre-swizzled global
// source, linear LDS dest, swizzled ds_read slot) -> <=2-way conflicts (free).
__device__ __forceinline__ void storeC(float* p, float v) { *p = v; }
__device__ __forceinline__ void storeC(bf16*  p, float v) { *p = __float2bfloat16(v); }

template<int ACT, typename CT>
__global__ __launch_bounds__(512, 2)
void gemm_bias_act(const bf16* __restrict__ A, const bf16* __restrict__ BT,
                   const float* __restrict__ bias, CT* __restrict__ C,
                   int M, int N, int K) {
  __shared__ __align__(16) short As[2*256*64];   // 64 KB
  __shared__ __align__(16) short Bs[2*256*64];   // 64 KB
  const int tid  = threadIdx.x;          // 0..511
  const int w    = tid >> 6;             // wave 0..7
  const int lane = tid & 63;
  const int fr   = lane & 15;
  const int quad = lane >> 4;
  const int la   = lane >> 3;            // staging sub-row 0..7
  const int gp   = lane & 7;             // physical 16B group (linear LDS dest)
  const int gl   = gp ^ la;              // logical (global) group = gp ^ (row&7)

  // XCD-aware bijective swizzle (nwg = 256, % 8 == 0)
  const int nbx = N >> 8;
  const int nwg = (M >> 8) * nbx;
  int fid = blockIdx.y * nbx + blockIdx.x;
  fid = (fid & 7) * (nwg >> 3) + (fid >> 3);
  const int m0 = (fid / nbx) * 256;
  const int n0 = (fid % nbx) * 256;
  const int wr = w >> 2, wc = w & 3;     // 2M x 4N wave grid

  f32x4 acc[8][4] = {};
  const int nit = K >> 7;                // iterations; 2 K-tiles (BK=64) each

  // A half h: tile-rows {h*64..h*64+63} U {128+h*64..}; per thread 2 loads.
#define STAGE_A(d, h, kt) do {                                              \
    const int kb_ = (kt)*64;                                                \
    _Pragma("unroll") for (int r_ = 0; r_ < 2; ++r_) {                      \
      const int row_ = r_*128 + (h)*64 + w*8 + la;                          \
      async_copy16(&As[((d)*256 + row_)*64 + gp*8],                         \
                   A + (size_t)(m0 + row_)*K + kb_ + gl*8);                 \
    } } while (0)
  // B half h: tile-rows (wc-block)*64 + h*32 + [0,32)
#define STAGE_B(d, h, kt) do {                                              \
    const int kb_ = (kt)*64;                                                \
    _Pragma("unroll") for (int r_ = 0; r_ < 2; ++r_) {                      \
      const int row_ = (r_*2 + (w>>2))*64 + (h)*32 + (w&3)*8 + la;          \
      async_copy16(&Bs[((d)*256 + row_)*64 + gp*8],                         \
                   BT + (size_t)(n0 + row_)*K + kb_ + gl*8);                \
    } } while (0)

#define VM4  asm volatile("s_waitcnt vmcnt(4)" ::: "memory")
#define VM0  asm volatile("s_waitcnt vmcnt(0)" ::: "memory")
#define NOWAIT ((void)0)
#define NOSTAGE ((void)0)

  // One phase: quadrant (qm,qn) of buffer d, staging STAGE_STMT, END_WAIT
  // placed after the MFMAs and before the closing barrier (so the following
  // barrier collectively certifies staged data for the NEXT phase's reads).
#define PHASE(d, qm, qn, STAGE_STMT, END_WAIT) {                            \
    short8 af_[4][2], bf_[2][2];                                            \
    const int pg0_ = (quad ^ (fr & 7)) * 8;                                 \
    const int pg1_ = ((4 + quad) ^ (fr & 7)) * 8;                           \
    const int ab_ = (d)*16384 + (wr*128 + fr)*64;                           \
    _Pragma("unroll") for (int m2_ = 0; m2_ < 4; ++m2_) {                   \
      af_[m2_][0] = *(const short8*)&As[ab_ + ((qm)*4 + m2_)*1024 + pg0_];  \
      af_[m2_][1] = *(const short8*)&As[ab_ + ((qm)*4 + m2_)*1024 + pg1_];  \
    }                                                                       \
    const int bb_ = (d)*16384 + (wc*64 + fr)*64;                            \
    _Pragma("unroll") for (int n2_ = 0; n2_ < 2; ++n2_) {                   \
      bf_[n2_][0] = *(const short8*)&Bs[bb_ + ((qn)*2 + n2_)*1024 + pg0_];  \
      bf_[n2_][1] = *(const short8*)&Bs[bb_ + ((qn)*2 + n2_)*1024 + pg1_];  \
    }                                                                       \
    STAGE_STMT;                                                             \
    asm volatile("s_barrier" ::: "memory");                                 \
    asm volatile("s_waitcnt lgkmcnt(0)" ::: "memory");                      \
    __builtin_amdgcn_s_setprio(1);                                          \
    _Pragma("unroll") for (int m2_ = 0; m2_ < 4; ++m2_)                     \
    _Pragma("unroll") for (int n2_ = 0; n2_ < 2; ++n2_)                     \
    _Pragma("unroll") for (int ks_ = 0; ks_ < 2; ++ks_)                     \
      acc[(qm)*4 + m2_][(qn)*2 + n2_] =                                     \
        __builtin_amdgcn_mfma_f32_16x16x32_bf16(af_[m2_][ks_], bf_[n2_][ks_],\
            acc[(qm)*4 + m2_][(qn)*2 + n2_], 0, 0, 0);                      \
    __builtin_amdgcn_s_setprio(0);                                          \
    END_WAIT;                                                               \
    asm volatile("s_barrier" ::: "memory");                                 \
  }

  // ---- prologue: buf0 <- tile 0 (4 halves), buf1 <- tile 1 h0 halves ----
  STAGE_A(0, 0, 0);
  STAGE_A(0, 1, 0);
  STAGE_B(0, 0, 0);
  STAGE_B(0, 1, 0);
  STAGE_A(1, 0, 1);
  STAGE_B(1, 0, 1);
  VM4;                                   // buf0 resident (leave buf1 h0 in flight)
  asm volatile("s_barrier" ::: "memory");

  // ---- main loop: iteration i computes tiles 2i (buf0) and 2i+1 (buf1) ----
  for (int i = 0; i < nit - 1; ++i) {
    const int ti = 2 * i;
    PHASE(0, 0, 0, STAGE_A(1, 1, ti + 1), NOWAIT)   // p0
    PHASE(0, 0, 1, STAGE_B(1, 1, ti + 1), NOWAIT)   // p1
    PHASE(0, 1, 0, STAGE_A(0, 0, ti + 2), NOWAIT)   // p2
    PHASE(0, 1, 1, STAGE_B(0, 0, ti + 2), VM4)      // p3: buf1 certified
    PHASE(1, 0, 0, STAGE_A(0, 1, ti + 2), NOWAIT)   // p4
    PHASE(1, 0, 1, STAGE_B(0, 1, ti + 2), NOWAIT)   // p5
    PHASE(1, 1, 0, STAGE_A(1, 0, ti + 3), NOWAIT)   // p6
    PHASE(1, 1, 1, STAGE_B(1, 0, ti + 3), VM4)      // p7: next buf0 certified
  }
  {
    const int ti = 2 * (nit - 1);
    PHASE(0, 0, 0, STAGE_A(1, 1, ti + 1), NOWAIT)
    PHASE(0, 0, 1, STAGE_B(1, 1, ti + 1), NOWAIT)
    PHASE(0, 1, 0, NOSTAGE, NOWAIT)
    PHASE(0, 1, 1, NOSTAGE, VM0)                    // drain: last tile certified
    PHASE(1, 0, 0, NOSTAGE, NOWAIT)
    PHASE(1, 0, 1, NOSTAGE, NOWAIT)
    PHASE(1, 1, 0, NOSTAGE, NOWAIT)
    PHASE(1, 1, 1, NOSTAGE, NOWAIT)
  }

  // ---- epilogue: C/D layout col(n)=lane&15, row(m)=quad*4+reg ----
  #pragma unroll
  for (int nf = 0; nf < 4; ++nf) {
    const int gn = n0 + wc*64 + nf*16 + fr;
    const float bv = bias[gn];
    #pragma unroll
    for (int mf = 0; mf < 8; ++mf) {
      const int gm = m0 + wr*128 + mf*16 + quad*4;
      #pragma unroll
      for (int r2 = 0; r2 < 4; ++r2) {
        float v = acc[mf][nf][r2] + bv;
        if (ACT) v = (v > 0.f) ? (v + 1.f) : __expf(v);   // elu(x)+1
        storeC(&C[(size_t)(gm + r2)*N + gn], v);
      }
    }
  }
#undef STAGE_A
#undef STAGE_B
#undef PHASE
#undef VM4
#undef VM0
#undef NOWAIT
#undef NOSTAGE
}

// ---------------- KV + K_sum partials via MFMA ----------------
// Per (n,h): KV[m][d] = sum_s V[s,m]*K[s,d]  (M=N=64, K=4096, split 16)
// Stage transposed tiles Kt[d][s],Vt[m][s] (64x64) with s-block XOR swizzle.
#define KV_SPLIT 16
__global__ __launch_bounds__(256)
void kv_kernel(const bf16* __restrict__ Kl, const bf16* __restrict__ V,
               float* __restrict__ KVp, float* __restrict__ Ksp) {
  const int b  = blockIdx.x;
  const int sp = b & (KV_SPLIT-1);
  const int nh = b >> 4;
  const int h = nh & (NHEADS-1), n = nh >> 4;
  const int tid = threadIdx.x;
  const int wave = tid >> 6, lane = tid & 63;
  const int fr = lane & 15, quad = lane >> 4;
  const int d = lane;                     // staging channel 0..63

  __shared__ __align__(16) short Kt[64*64];
  __shared__ __align__(16) short Vt[64*64];
  __shared__ float Ksl[4][64];

  const ushort_t* Kg = (const ushort_t*)Kl;
  const ushort_t* Vg = (const ushort_t*)V;

  f32x4 acc[4] = {};
  float ksacc = 0.f;
  const int s_base = sp * (SEQLEN / KV_SPLIT);   // 256 s-rows per block

  for (int c0 = 0; c0 < 256; c0 += 64) {
    __syncthreads();
    #pragma unroll
    for (int i = 0; i < 2; ++i) {
      const int s8 = wave*2 + i;          // s-block 0..7
      const size_t gbase = ((size_t)(n*SEQLEN + s_base + c0 + s8*8))*D_MODEL + h*DH + d;
      short8 pk, pv;
      #pragma unroll
      for (int e = 0; e < 8; ++e) {
        const ushort_t ku = Kg[gbase + (size_t)e*D_MODEL];   // 64 lanes x 2B contiguous
        const ushort_t vu = Vg[gbase + (size_t)e*D_MODEL];
        pk[e] = (short)ku;
        pv[e] = (short)vu;
        ksacc += bfbits_to_f(ku);
      }
      const int wofs = d*64 + ((s8 ^ (d & 7)) << 3);   // swizzled: 2-way-free b128 write
      *(short8*)&Kt[wofs] = pk;
      *(short8*)&Vt[wofs] = pv;
    }
    __syncthreads();
    #pragma unroll
    for (int k0 = 0; k0 < 2; ++k0) {
      const int s8a = k0*4 + quad;
      const int arow = wave*16 + fr;      // m-strip per wave
      const short8 afr = *(const short8*)&Vt[arow*64 + ((s8a ^ (arow & 7)) << 3)];
      #pragma unroll
      for (int j = 0; j < 4; ++j) {
        const int brow = j*16 + fr;
        const short8 bfr = *(const short8*)&Kt[brow*64 + ((s8a ^ (brow & 7)) << 3)];
        acc[j] = __builtin_amdgcn_mfma_f32_16x16x32_bf16(afr, bfr, acc[j], 0, 0, 0);
      }
    }
  }

  // Ksum partial: each thread covered (d = lane, s-blocks wave*2..wave*2+1) fully
  Ksl[wave][d] = ksacc;
  __syncthreads();
  if (tid < 64)
    Ksp[b*64 + tid] = Ksl[0][tid] + Ksl[1][tid] + Ksl[2][tid] + Ksl[3][tid];

  // KV partial: m = wave*16 + quad*4 + r, col d = j*16 + fr
  float* outp = KVp + (size_t)b*4096;
  #pragma unroll
  for (int j = 0; j < 4; ++j)
    #pragma unroll
    for (int r = 0; r < 4; ++r)
      outp[(wave*16 + quad*4 + r)*64 + j*16 + fr] = acc[j][r];
}

// ---------------- reduce 16 partials -> KV, Ksum ----------------
__global__ __launch_bounds__(256)
void kv_reduce(const float* __restrict__ KVp, const float* __restrict__ Ksp,
               float* __restrict__ KV, float* __restrict__ Ksum) {
  const int c  = blockIdx.x;    // 0..3
  const int nh = blockIdx.y;    // 0..63
  const int e = c*1024 + threadIdx.x*4;
  f32x4 s = {};
  #pragma unroll
  for (int sp = 0; sp < KV_SPLIT; ++sp)
    s += *(const f32x4*)(KVp + ((size_t)(nh*KV_SPLIT + sp))*4096 + e);
  *(f32x4*)(KV + (size_t)nh*4096 + e) = s;
  if (c == 0 && threadIdx.x < 64) {
    float ks = 0.f;
    #pragma unroll
    for (int sp = 0; sp < KV_SPLIT; ++sp)
      ks += Ksp[(nh*KV_SPLIT + sp)*64 + threadIdx.x];
    Ksum[nh*64 + threadIdx.x] = ks;
  }
}

// ---------------- V_lin = Z * (Q_lin . KV)  — MFMA batched GEMM ----------------
__device__ __forceinline__ int bswz(int row, int d) {   // XOR-swizzled LDS index
  return row*64 + ((((d >> 3) ^ (row & 7)) << 3) | (d & 7));
}

__global__ __launch_bounds__(256)
void vlin_kernel(const bf16* __restrict__ Ql, const float* __restrict__ KV,
                 const float* __restrict__ Ksum, bf16* __restrict__ Vl) {
  const int lc = blockIdx.x;            // l-chunk of 128 rows (32 total)
  const int nh = blockIdx.y;            // n*NHEADS + h
  const int h = nh & (NHEADS-1), n = nh >> 4;
  const int tid = threadIdx.x, wave = tid >> 6, lane = tid & 63;
  const int fr = lane & 15, quad = lane >> 4;

  __shared__ __align__(16) short Bs2[144*64];
  __shared__ float Zs[128];

  // ---- stage B (f32 KV/Ksum -> hi/lo bf16, swizzled) ----
  const float* kvp = KV + (size_t)nh*DH*DH;
  for (int i = tid; i < DH*DH; i += 256) {
    const int m = i >> 6, d = i & 63;
    const float v = kvp[i];
    const short hi = f2bf_bits(v);
    bf16 hb; __builtin_memcpy(&hb, &hi, 2);
    const short lo = f2bf_bits(v - __bfloat162float(hb));
    Bs2[bswz(m, d)]      = hi;
    Bs2[bswz(64 + m, d)] = lo;
  }
  if (tid < 64) {
    const float v = Ksum[nh*DH + tid];
    const short hi = f2bf_bits(v);
    bf16 hb; __builtin_memcpy(&hb, &hi, 2);
    const short lo = f2bf_bits(v - __bfloat162float(hb));
    Bs2[bswz(128, tid)] = hi;
    Bs2[bswz(129, tid)] = lo;
  }
  for (int i = tid; i < 14*64; i += 256)
    Bs2[(130 + (i >> 6))*64 + (i & 63)] = 0;
  __syncthreads();

  // ---- A fragments: direct global -> VGPR ----
  const int l0 = lc * 128;
  const size_t qbase = ((size_t)(n*SEQLEN) + l0)*D_MODEL + h*DH;
  short8 afr[2][2];
  #pragma unroll
  for (int i = 0; i < 2; ++i)
    #pragma unroll
    for (int ks = 0; ks < 2; ++ks)
      afr[i][ks] = *(const short8*)(Ql + qbase +
                     (size_t)(wave*32 + i*16 + fr)*D_MODEL + ks*32 + quad*8);

  f32x4 acc[2][9] = {};
  #pragma unroll
  for (int ks = 0; ks < 2; ++ks) {
    #pragma unroll
    for (int j = 0; j < 9; ++j) {
      const int brow = j*16 + fr;
      const short8 bfr = *(const short8*)&Bs2[brow*64 +
                            (((ks*4 + quad) ^ (fr & 7)) << 3)];
      #pragma unroll
      for (int i = 0; i < 2; ++i)
        acc[i][j] = __builtin_amdgcn_mfma_f32_16x16x32_bf16(afr[i][ks], bfr, acc[i][j], 0, 0, 0);
    }
  }

  // ---- Z[row] = 1/(P[row,128]+P[row,129]+eps) ----
  #pragma unroll
  for (int i = 0; i < 2; ++i) {
    #pragma unroll
    for (int r2 = 0; r2 < 4; ++r2) {
      const float v = acc[i][8][r2];
      const float vp = v + __shfl_xor(v, 1, 64);
      if (fr == 0) Zs[wave*32 + i*16 + quad*4 + r2] = 1.0f / (vp + EPSV);
    }
  }
  __syncthreads();

  // ---- scale + store ----
  #pragma unroll
  for (int i = 0; i < 2; ++i) {
    #pragma unroll
    for (int r2 = 0; r2 < 4; ++r2) {
      const int rloc = wave*32 + i*16 + quad*4 + r2;
      const float z = Zs[rloc];
      #pragma unroll
      for (int j = 0; j < 4; ++j) {
        const float num = acc[i][j][r2] + acc[i][4 + j][r2];
        Vl[qbase + (size_t)rloc*D_MODEL + j*16 + fr] = __float2bfloat16(num * z);
      }
    }
  }
}

// ---------------- launch ----------------
extern "C" void kernel_launch(void* const* d_in, const int* in_sizes, int n_in,
                              void* d_out, int out_size, void* d_ws, size_t ws_size,
                              hipStream_t stream) {
  const float* q  = (const float*)d_in[0];
  const float* k  = (const float*)d_in[1];
  const float* v  = (const float*)d_in[2];
  const float* Wq = (const float*)d_in[3];
  const float* bq = (const float*)d_in[4];
  const float* Wk = (const float*)d_in[5];
  const float* bk = (const float*)d_in[6];
  const float* Wv = (const float*)d_in[7];
  const float* bv = (const float*)d_in[8];
  const float* Wo = (const float*)d_in[9];
  const float* bo = (const float*)d_in[10];
  float* out = (float*)d_out;

  bf16* WqT = (bf16*)d_ws;
  bf16* WkT = WqT + (size_t)D_MODEL*D_MODEL;
  bf16* WvT = WkT + (size_t)D_MODEL*D_MODEL;
  bf16* WoT = WvT + (size_t)D_MODEL*D_MODEL;
  bf16* Xb  = WoT + (size_t)D_MODEL*D_MODEL;   // 32 MB staging, reused q->k->v
  bf16* Ql  = Xb  + (size_t)MROWS*D_MODEL;
  bf16* Kl  = Ql  + (size_t)MROWS*D_MODEL;
  bf16* Vb  = Kl  + (size_t)MROWS*D_MODEL;
  bf16* Vl  = Kl;                              // reuse: K_lin dead after kv_kernel
  float* KV = (float*)(Vb + (size_t)MROWS*D_MODEL);
  float* Ks = KV + (size_t)NBATCH*NHEADS*DH*DH;
  // kv partials overlay the dead Xb region (dead after the V-projection GEMM)
  float* KVp = (float*)Xb;                                   // 16 MB
  float* Ksp = KVp + (size_t)NBATCH*NHEADS*KV_SPLIT*DH*DH;   // 256 KB

  transpose4<<<dim3(32,32,4), dim3(32,32,1), 0, stream>>>(Wq,Wk,Wv,Wo, WqT,WkT,WvT,WoT);

  const int nconv4 = MROWS*D_MODEL/4;
  dim3 gb(512), gg(D_MODEL/256, MROWS/256);    // (4, 64) = 256 blocks = 1/CU

  cvt_bf16<<<nconv4/256, 256, 0, stream>>>(q, Xb);
  gemm_bias_act<1,bf16><<<gg, gb, 0, stream>>>(Xb, WqT, bq, Ql, MROWS, D_MODEL, D_MODEL);
  cvt_bf16<<<nconv4/256, 256, 0, stream>>>(k, Xb);
  gemm_bias_act<1,bf16><<<gg, gb, 0, stream>>>(Xb, WkT, bk, Kl, MROWS, D_MODEL, D_MODEL);
  cvt_bf16<<<nconv4/256, 256, 0, stream>>>(v, Xb);
  gemm_bias_act<0,bf16><<<gg, gb, 0, stream>>>(Xb, WvT, bv, Vb, MROWS, D_MODEL, D_MODEL);

  kv_kernel<<<dim3(NBATCH*NHEADS*KV_SPLIT), dim3(256), 0, stream>>>(Kl, Vb, KVp, Ksp);
  kv_reduce<<<dim3(4, NBATCH*NHEADS), dim3(256), 0, stream>>>(KVp, Ksp, KV, Ks);
  vlin_kernel<<<dim3(SEQLEN/128, NBATCH*NHEADS), dim3(256), 0, stream>>>(Ql, KV, Ks, Vl);

  gemm_bias_act<0,float><<<gg, gb, 0, stream>>>(Vl, WoT, bo, out, MROWS, D_MODEL, D_MODEL);
}